// Round 13
// baseline (154.551 us; speedup 1.0000x reference)
//
#include <hip/hip_runtime.h>
#include <stdint.h>

#define N_E 512
#define DIM 64
#define HW  4096                 // 64*64
#define NPTS (32 * HW)           // 131072 points
#define OUT_ELEMS (NPTS * DIM)   // 8388608

typedef float  f32x4  __attribute__((ext_vector_type(4)));
typedef short  bf16x8 __attribute__((ext_vector_type(8)));

// ws layout: [0,2048) e2 fp32; [2048, 2048+64K) emb-high frags; then emb-low
#define WS_FH_OFF 2048
#define WS_FL_OFF (2048 + 65536)

__device__ __forceinline__ unsigned short f2bf_rne(float f) {
    union { float f; uint32_t u; } c; c.f = f;
    uint32_t r = c.u + 0x7FFFu + ((c.u >> 16) & 1u);
    return (unsigned short)(r >> 16);
}
__device__ __forceinline__ float bf2f(unsigned short h) {
    union { float f; uint32_t u; } c; c.u = ((uint32_t)h) << 16;
    return c.f;
}

// Prep: out[0]=0, e2[512]=||emb_row||^2, pack emb into bf16 high/low
// A-fragments for mfma_f32_16x16x32_bf16 (unchanged from round 12).
__global__ __launch_bounds__(256) void vq_prep(const float* __restrict__ emb,
                                               float* __restrict__ out,
                                               void* __restrict__ ws) {
    const int tid = blockIdx.x * 256 + threadIdx.x;
    float*  e2 = (float*)ws;
    bf16x8* fh = (bf16x8*)((char*)ws + WS_FH_OFF);
    bf16x8* fl = (bf16x8*)((char*)ws + WS_FL_OFF);
    if (tid == 0) out[0] = 0.0f;
    if (tid < 512) {
        const float4* rp = (const float4*)(emb + tid * DIM);
        float s = 0.f;
#pragma unroll
        for (int j = 0; j < 16; ++j) {
            float4 f = rp[j];
            s = fmaf(f.x, f.x, s);
            s = fmaf(f.y, f.y, s);
            s = fmaf(f.z, f.z, s);
            s = fmaf(f.w, f.w, s);
        }
        e2[tid] = s;
    }
    const int u = tid - 512;
    if (u >= 0 && u < 4096) {
        const int n = u >> 7, rem = u & 127, s = rem >> 6, l = rem & 63;
        const int entry = n * 16 + (l & 15);
        const int kb    = s * 32 + 8 * (l >> 4);
        const float* src = emb + entry * DIM + kb;
        bf16x8 hv, lv;
#pragma unroll
        for (int j = 0; j < 8; ++j) {
            float v = src[j];
            unsigned short h = f2bf_rne(v);
            float res = v - bf2f(h);
            hv[j] = (short)h;
            lv[j] = (short)f2bf_rne(res);
        }
        const int idx = (n * 2 + s) * 64 + l;
        fh[idx] = hv;
        fl[idx] = lv;
    }
}

// Main: ROUND-12 LESSON: 64 pts/wave = 2048 waves = 2/SIMD, no prefetch
// -> per-tile L2-latency chain exposed (MfmaUtil 15%, VALU 21%, Occ 18%).
// Now: 32 pts/wave -> 4096 waves = 4/SIMD (launch_bounds(256,4)), and the
// 4 frag loads are register-double-buffered (prefetch tile (n+1)&31 while
// computing tile n) so the s_waitcnt lands after 12 MFMAs of cover.
// Numerics bit-identical to round 12 (same MFMA order, same d assembly,
// same tie-break) — only work ownership/scheduling changed.
__global__ __launch_bounds__(256, 4) void vq_main(
    const float* __restrict__ z,    // [32, 64, 64, 64] NCHW
    const float* __restrict__ emb,  // [512, 64] fp32 (epilogue gather)
    const void*  __restrict__ ws,   // e2 + fragments from vq_prep
    float* __restrict__ out)        // [0]=loss, [1..]=z_q_st NCHW
{
    const int t   = threadIdx.x;
    const int l   = t & 63;
    const int wv  = t >> 6;
    const int grp = l >> 4;       // 0..3: entry-row group / channel group
    const int col = l & 15;       // point within a 16-point tile

    const float*  e2g = (const float*)ws;
    const bf16x8* fh  = (const bf16x8*)((const char*)ws + WS_FH_OFF);
    const bf16x8* fl  = (const bf16x8*)((const char*)ws + WS_FL_OFF);

    __shared__ float se2[N_E];
    se2[t]       = e2g[t];
    se2[256 + t] = e2g[256 + t];
    __syncthreads();

    const int gw  = blockIdx.x * 4 + wv;    // wave id 0..4095
    const int p0  = gw * 32;                // 32 points, never crosses b
    const int b   = p0 >> 12;
    const int hw0 = p0 & 4095;
    const float* zb = z + (size_t)b * DIM * HW + hw0;

    // ---- load z, build bf16-split B fragments + z2 per point-tile ----
    bf16x8 zh[2][2], zl[2][2];
    float  z2p[2];
#pragma unroll
    for (int pt = 0; pt < 2; ++pt) {
        float part = 0.f;
#pragma unroll
        for (int s = 0; s < 2; ++s) {
            bf16x8 hv, lv;
#pragma unroll
            for (int j = 0; j < 8; ++j) {
                const int ch = s * 32 + 8 * grp + j;
                float v = zb[(size_t)ch * HW + pt * 16 + col];
                part = fmaf(v, v, part);
                unsigned short h = f2bf_rne(v);
                float res = v - bf2f(h);
                hv[j] = (short)h;
                lv[j] = (short)f2bf_rne(res);
            }
            zh[pt][s] = hv;
            zl[pt][s] = lv;
        }
        part += __shfl_xor(part, 16, 64);   // combine the 4 channel groups
        part += __shfl_xor(part, 32, 64);
        z2p[pt] = part;                     // full ||z||^2 of point (pt,col)
    }

    float dmin[2] = {3.4e38f, 3.4e38f};
    int   imin[2] = {0, 0};

    // ---- scan 32 entry-tiles, register-double-buffered frag loads ----
    bf16x8 ceh0 = fh[l], ceh1 = fh[64 + l];
    bf16x8 cel0 = fl[l], cel1 = fl[64 + l];
#pragma unroll 1
    for (int n = 0; n < 32; ++n) {
        const int nb = ((n + 1) & 31) * 128;     // wraps: uniform pattern
        bf16x8 neh0 = fh[nb + l], neh1 = fh[nb + 64 + l];
        bf16x8 nel0 = fl[nb + l], nel1 = fl[nb + 64 + l];

        const int ebase = n * 16 + grp * 4;
        const float4 e2q = *(const float4*)(&se2[ebase]);
#pragma unroll
        for (int pt = 0; pt < 2; ++pt) {
            f32x4 acc = {0.f, 0.f, 0.f, 0.f};
            acc = __builtin_amdgcn_mfma_f32_16x16x32_bf16(ceh0, zh[pt][0], acc, 0, 0, 0);
            acc = __builtin_amdgcn_mfma_f32_16x16x32_bf16(ceh1, zh[pt][1], acc, 0, 0, 0);
            acc = __builtin_amdgcn_mfma_f32_16x16x32_bf16(cel0, zh[pt][0], acc, 0, 0, 0);
            acc = __builtin_amdgcn_mfma_f32_16x16x32_bf16(cel1, zh[pt][1], acc, 0, 0, 0);
            acc = __builtin_amdgcn_mfma_f32_16x16x32_bf16(ceh0, zl[pt][0], acc, 0, 0, 0);
            acc = __builtin_amdgcn_mfma_f32_16x16x32_bf16(ceh1, zl[pt][1], acc, 0, 0, 0);
            const float zz = z2p[pt];
            float d0 = fmaf(-2.f, acc[0], zz + e2q.x);
            float d1 = fmaf(-2.f, acc[1], zz + e2q.y);
            float d2 = fmaf(-2.f, acc[2], zz + e2q.z);
            float d3 = fmaf(-2.f, acc[3], zz + e2q.w);
            if (d0 < dmin[pt]) { dmin[pt] = d0; imin[pt] = ebase;     }
            if (d1 < dmin[pt]) { dmin[pt] = d1; imin[pt] = ebase + 1; }
            if (d2 < dmin[pt]) { dmin[pt] = d2; imin[pt] = ebase + 2; }
            if (d3 < dmin[pt]) { dmin[pt] = d3; imin[pt] = ebase + 3; }
        }
        ceh0 = neh0; ceh1 = neh1; cel0 = nel0; cel1 = nel1;
    }

    // ---- cross-lane combine (ties -> smaller index = global first-index) ----
#pragma unroll
    for (int pt = 0; pt < 2; ++pt) {
        float d = dmin[pt]; int i = imin[pt];
        float da = __shfl_xor(d, 16, 64); int ia = __shfl_xor(i, 16, 64);
        if (da < d || (da == d && ia < i)) { d = da; i = ia; }
        float db = __shfl_xor(d, 32, 64); int ib = __shfl_xor(i, 32, 64);
        if (db < d || (db == d && ib < i)) { d = db; i = ib; }
        dmin[pt] = d; imin[pt] = i;
    }

    // ---- loss: sum dmin once per point (group 0 only), wave-reduce ----
    float acc_l = (grp == 0) ? (dmin[0] + dmin[1]) : 0.f;
#pragma unroll
    for (int o = 32; o > 0; o >>= 1) acc_l += __shfl_down(acc_l, o, 64);
    if (l == 0) atomicAdd(out, acc_l * (1.25f / (float)OUT_ELEMS));

    // ---- write z_q_st: 2 lanes per point, each stores 32 channels ----
    const int pp = l & 31;                 // point within wave
    const int hh = l >> 5;                 // channel half
    const int w  = imin[pp >> 4];          // lane's col == pp&15  ✓
    const float4* q4 = (const float4*)(emb + w * DIM + hh * 32);
    float* ob = out + 1 + (size_t)b * DIM * HW + hw0 + pp;
#pragma unroll
    for (int j = 0; j < 8; ++j) {
        float4 v = q4[j];
        ob[(size_t)(hh * 32 + 4 * j + 0) * HW] = v.x;
        ob[(size_t)(hh * 32 + 4 * j + 1) * HW] = v.y;
        ob[(size_t)(hh * 32 + 4 * j + 2) * HW] = v.z;
        ob[(size_t)(hh * 32 + 4 * j + 3) * HW] = v.w;
    }
}

extern "C" void kernel_launch(void* const* d_in, const int* in_sizes, int n_in,
                              void* d_out, int out_size, void* d_ws, size_t ws_size,
                              hipStream_t stream) {
    const float* z   = (const float*)d_in[0];
    const float* emb = (const float*)d_in[1];
    float* out = (float*)d_out;

    vq_prep<<<18, 256, 0, stream>>>(emb, out, d_ws);
    vq_main<<<1024, 256, 0, stream>>>(z, emb, d_ws, out);
}